// Round 6
// baseline (10808.067 us; speedup 1.0000x reference)
//
#include <hip/hip_runtime.h>

#define B_ 128
#define T_ 2048
#define D_ 128
#define H_ 512
#define L_ 10
#define NPAIR 4   // group pairs: WG serves groups (p, p+4)
#define NS 16     // gate-slice WGs per group
#define GB 16     // batches per group (MFMA N)
#define HS 32     // hidden units per slice
#define NKK 20    // K-steps of 32 (16 h-steps + 4 x-steps)

typedef __attribute__((ext_vector_type(8))) short short8;
typedef __attribute__((ext_vector_type(4))) float f32x4;
typedef unsigned long long u64;

__device__ __forceinline__ unsigned short f2bf(float f) {
    union { float f; unsigned u; } v; v.f = f;
    unsigned r = v.u + 0x7fffu + ((v.u >> 16) & 1u);
    return (unsigned short)(r >> 16);
}
__device__ __forceinline__ float fast_sig(float x) {
    return 1.f / (1.f + __expf(-x));
}
__device__ __forceinline__ float fast_tanh(float x) {
    return 1.f - 2.f / (__expf(2.f * x) + 1.f);
}

// ---- verified R1 agent-scope comm primitives (NO cache-scope tricks) ----
__device__ __forceinline__ u64 h_ld(const u64* p) {
    return __hip_atomic_load(p, __ATOMIC_RELAXED, __HIP_MEMORY_SCOPE_AGENT);
}
__device__ __forceinline__ void h_st(u64* p, u64 v) {
    __hip_atomic_store(p, v, __ATOMIC_RELAXED, __HIP_MEMORY_SCOPE_AGENT);
}
__device__ __forceinline__ void f_st(unsigned* p, unsigned v) {
    __hip_atomic_store(p, v, __ATOMIC_RELAXED, __HIP_MEMORY_SCOPE_AGENT);
}
__device__ __forceinline__ void poll2(const unsigned* q0, const unsigned* q1,
                                      unsigned tt, int& budget) {
    for (;;) {
        const unsigned a = __hip_atomic_load(q0, __ATOMIC_RELAXED,
                                             __HIP_MEMORY_SCOPE_AGENT);
        const unsigned b = __hip_atomic_load(q1, __ATOMIC_RELAXED,
                                             __HIP_MEMORY_SCOPE_AGENT);
        if (((a >= tt) & (b >= tt)) || --budget <= 0) break;
    }
    __asm__ __volatile__("" ::: "memory");
}
__device__ __forceinline__ short8 packx(const float4 a, const float4 b) {
    short8 v;
    v[0]=(short)f2bf(a.x); v[1]=(short)f2bf(a.y);
    v[2]=(short)f2bf(a.z); v[3]=(short)f2bf(a.w);
    v[4]=(short)f2bf(b.x); v[5]=(short)f2bf(b.y);
    v[6]=(short)f2bf(b.z); v[7]=(short)f2bf(b.w);
    return v;
}

// Persistent two-stream LSTM. 64 WGs = 16 slices x 4 pairs; each WG runs
// batch groups gA=p and gB=p+4 on the SAME weight fragments (weights depend
// only on slice). Per iteration: MFMA/cell A -> per-wave publish A ->
// poll+issue A(t+1) reloads (fly under MFMA B) -> MFMA/cell B -> publish B
// -> poll+issue B(t+1) reloads (fly under next MFMA A). All cross-WG ops are
// the R1-verified agent-scope relaxed atomics; publishes are per-wave flags
// after each wave's own vmcnt(0) drain (no barrier on the publish path).
__global__ __launch_bounds__(512, 2) void lstm_kernel(
    const float* __restrict__ x, const float* __restrict__ W_ih,
    const float* __restrict__ W_hh, const float* __restrict__ bias,
    u64* h_buf,               // [2][16384] u64 = [2][128][512] bf16
    unsigned int* flags,      // [8][128] per-(group, slice*8+wave) counters
    float* __restrict__ hfin) // [128][512] fp32
{
    const int p    = blockIdx.x & (NPAIR - 1);
    const int s    = blockIdx.x >> 2;
    const int gA   = p, gB = p + NPAIR;
    const int tid  = threadIdx.x;
    const int lane = tid & 63;
    const int w    = tid >> 6;     // wave 0..7
    const int quad = lane >> 4;    // 0..3
    const int col  = lane & 15;    // MFMA N index (batch within group)

    __shared__ __align__(16) short BstA[NKK * 64 * 8];   // 20480 B
    __shared__ __align__(16) short BstB[NKK * 64 * 8];   // 20480 B

    // ---- one-time: gate-interleaved weight A-fragments (slice-only dep) ----
    short8 wfrag[NKK];
    {
        const int m = col;
        const int r = (m & 3) * 512 + s * HS + w * 4 + (m >> 2);
        #pragma unroll
        for (int kk = 0; kk < NKK; ++kk) {
            const int k0 = kk * 32 + quad * 8;
            short8 v;
            #pragma unroll
            for (int j = 0; j < 8; ++j) {
                const int k = k0 + j;
                const float f = (k < 512) ? W_hh[r * 512 + k]
                                          : W_ih[r * 128 + (k - 512)];
                v[j] = (short)f2bf(f);
            }
            wfrag[kk] = v;
        }
    }

    const int hu_g = s * HS + w * 4 + quad;
    const float bi  = bias[0 * 512 + hu_g];
    const float bfv = bias[1 * 512 + hu_g];
    const float bg  = bias[2 * 512 + hu_g];
    const float bo  = bias[3 * 512 + hu_g];
    float cA = 0.f, cB = 0.f;

    // x staging addresses (waves 0..3)
    const float *xbA = nullptr, *xbB = nullptr;
    int xc = 0;
    if (tid < 256) {
        const int kk = tid >> 6, ln = tid & 63;
        const int n  = ln & 15;
        const int k0 = kk * 32 + (ln >> 4) * 8;
        xbA = x + (size_t)(gA * GB + n) * T_ * D_ + k0;
        xbB = x + (size_t)(gB * GB + n) * T_ * D_ + k0;
        xc  = (16 + kk) * 64 + ln;
    }

    // h fragment addressing (u64 units)
    const int hc0 = tid, hc1 = tid + 512;
    auto hoff = [](int c, int g) -> size_t {
        const int ln = c & 63, kk = c >> 6;
        return (size_t)(g * GB + (ln & 15)) * 128 + (size_t)(kk * 8 + (ln >> 4) * 2);
    };
    u64* hA0 = h_buf + hoff(hc0, gA);
    u64* hA1 = h_buf + hoff(hc1, gA);
    u64* hB0 = h_buf + hoff(hc0, gB);
    u64* hB1 = h_buf + hoff(hc1, gB);
    u64* hdA = h_buf + (size_t)(gA * GB + col) * 128 + s * 8 + w;
    u64* hdB = h_buf + (size_t)(gB * GB + col) * 128 + s * 8 + w;
    unsigned* pfA = flags + gA * 128 + s * 8 + w;
    unsigned* pfB = flags + gB * 128 + s * 8 + w;
    const unsigned* qA0 = flags + gA * 128 + lane; const unsigned* qA1 = qA0 + 64;
    const unsigned* qB0 = flags + gB * 128 + lane; const unsigned* qB1 = qB0 + 64;

    // ---- prologue: LDS_A = h(0)=0 + x_A(0); LDS_B x(0); issue hB(0) loads ----
    {
        short8 z = {0, 0, 0, 0, 0, 0, 0, 0};
        *(short8*)&BstA[hc0 * 8] = z;
        *(short8*)&BstA[hc1 * 8] = z;
    }
    if (tid < 256) {
        const float4* pa = (const float4*)xbA;
        *(short8*)&BstA[xc * 8] = packx(pa[0], pa[1]);
        const float4* pb = (const float4*)xbB;
        *(short8*)&BstB[xc * 8] = packx(pb[0], pb[1]);
    }
    u64 rB0 = h_ld(hB0), rB1 = h_ld(hB0 + 1);
    u64 rB2 = h_ld(hB1), rB3 = h_ld(hB1 + 1);
    float4 xb0p = {0,0,0,0}, xb1p = {0,0,0,0};
    __syncthreads();

    int budget = 1 << 24;   // anti-hang guard: degrade to wrong answer, never hang

    for (int t = 0; t < T_; ++t) {
        const unsigned tt = (unsigned)(t + 1);
        const size_t   pn = (size_t)((t + 1) & 1) * 16384;

        // (1) MFMA A(t)                         [hB(t) loads still in flight]
        f32x4 acc0 = {0,0,0,0}, acc1 = {0,0,0,0};
        #pragma unroll
        for (int kk = 0; kk < NKK; kk += 2) {
            const short8 b0 = *(const short8*)&BstA[(kk * 64 + lane) * 8];
            const short8 b1 = *(const short8*)&BstA[((kk + 1) * 64 + lane) * 8];
            acc0 = __builtin_amdgcn_mfma_f32_16x16x32_bf16(wfrag[kk], b0, acc0, 0, 0, 0);
            acc1 = __builtin_amdgcn_mfma_f32_16x16x32_bf16(wfrag[kk + 1], b1, acc1, 0, 0, 0);
        }
        // (2) cell A; issue h_A(t+1) stores
        {
            const float gi = acc0[0] + acc1[0] + bi;
            const float gf = acc0[1] + acc1[1] + bfv;
            const float gg = acc0[2] + acc1[2] + bg;
            const float go = acc0[3] + acc1[3] + bo;
            cA = fast_sig(gf) * cA + fast_sig(gi) * fast_tanh(gg);
            const float h  = fast_sig(go) * fast_tanh(cA);
            const float h1 = __shfl_down(h, 16, 64);
            const float h2 = __shfl_down(h, 32, 64);
            const float h3 = __shfl_down(h, 48, 64);
            if (quad == 0)
                h_st(hdA + pn, (u64)f2bf(h)          | ((u64)f2bf(h1) << 16)
                             | ((u64)f2bf(h2) << 32) | ((u64)f2bf(h3) << 48));
            if (t == T_ - 1) hfin[(size_t)(gA * GB + col) * H_ + hu_g] = h;
        }
        // (2b) drain own stores (also hB(t) loads, long landed); per-wave publish
        asm volatile("s_waitcnt vmcnt(0)" ::: "memory");
        if (lane == 0) f_st(pfA, tt);
        // (3) LDS_B <- h_B(t) (+ x_B(t) staged last iteration)
        {
            union { u64 q[2]; short8 v; } u0, u1;
            u0.q[0] = rB0; u0.q[1] = rB1; u1.q[0] = rB2; u1.q[1] = rB3;
            *(short8*)&BstB[hc0 * 8] = u0.v;
            *(short8*)&BstB[hc1 * 8] = u1.v;
        }
        if (t > 0 && tid < 256) *(short8*)&BstB[xc * 8] = packx(xb0p, xb1p);
        // (4)
        __syncthreads();
        // (5) issue x_A(t+1) loads (hide under poll + MFMA B)
        float4 xa0 = {0,0,0,0}, xa1 = {0,0,0,0};
        if (tid < 256) {
            const int tx = (t + 1 < T_) ? t + 1 : 0;   // clamp: no OOB read
            const float4* pa = (const float4*)(xbA + (size_t)tx * D_);
            xa0 = pa[0]; xa1 = pa[1];
        }
        __builtin_amdgcn_sched_barrier(0);
        // (6) poll A(t+1): 128 per-wave flags, 2 per lane
        poll2(qA0, qA1, tt, budget);
        // (7) issue h_A(t+1) loads -> fly under MFMA B
        u64 a0 = h_ld(hA0 + pn), a1 = h_ld(hA0 + pn + 1);
        u64 a2 = h_ld(hA1 + pn), a3 = h_ld(hA1 + pn + 1);
        __builtin_amdgcn_sched_barrier(0);
        // (8) MFMA B(t)
        acc0 = (f32x4){0,0,0,0}; acc1 = (f32x4){0,0,0,0};
        #pragma unroll
        for (int kk = 0; kk < NKK; kk += 2) {
            const short8 b0 = *(const short8*)&BstB[(kk * 64 + lane) * 8];
            const short8 b1 = *(const short8*)&BstB[((kk + 1) * 64 + lane) * 8];
            acc0 = __builtin_amdgcn_mfma_f32_16x16x32_bf16(wfrag[kk], b0, acc0, 0, 0, 0);
            acc1 = __builtin_amdgcn_mfma_f32_16x16x32_bf16(wfrag[kk + 1], b1, acc1, 0, 0, 0);
        }
        // (9) cell B; issue h_B(t+1) stores
        {
            const float gi = acc0[0] + acc1[0] + bi;
            const float gf = acc0[1] + acc1[1] + bfv;
            const float gg = acc0[2] + acc1[2] + bg;
            const float go = acc0[3] + acc1[3] + bo;
            cB = fast_sig(gf) * cB + fast_sig(gi) * fast_tanh(gg);
            const float h  = fast_sig(go) * fast_tanh(cB);
            const float h1 = __shfl_down(h, 16, 64);
            const float h2 = __shfl_down(h, 32, 64);
            const float h3 = __shfl_down(h, 48, 64);
            if (quad == 0)
                h_st(hdB + pn, (u64)f2bf(h)          | ((u64)f2bf(h1) << 16)
                             | ((u64)f2bf(h2) << 32) | ((u64)f2bf(h3) << 48));
            if (t == T_ - 1) hfin[(size_t)(gB * GB + col) * H_ + hu_g] = h;
        }
        // (9b) drain (hA loads + xA loads + own hB stores); per-wave publish B
        asm volatile("s_waitcnt vmcnt(0)" ::: "memory");
        if (lane == 0) f_st(pfB, tt);
        // LDS_A <- h_A(t+1) + x_A(t+1)
        {
            union { u64 q[2]; short8 v; } u0, u1;
            u0.q[0] = a0; u0.q[1] = a1; u1.q[0] = a2; u1.q[1] = a3;
            *(short8*)&BstA[hc0 * 8] = u0.v;
            *(short8*)&BstA[hc1 * 8] = u1.v;
        }
        if (tid < 256) *(short8*)&BstA[xc * 8] = packx(xa0, xa1);
        // (10)
        __syncthreads();
        // (11) issue x_B(t+1) loads (persist to next iteration's step 3)
        if (tid < 256) {
            const int tx = (t + 1 < T_) ? t + 1 : 0;
            const float4* pb = (const float4*)(xbB + (size_t)tx * D_);
            xb0p = pb[0]; xb1p = pb[1];
        }
        __builtin_amdgcn_sched_barrier(0);
        // (12) poll B(t+1)
        poll2(qB0, qB1, tt, budget);
        // (13) issue h_B(t+1) loads -> fly under next iteration's MFMA A
        rB0 = h_ld(hB0 + pn); rB1 = h_ld(hB0 + pn + 1);
        rB2 = h_ld(hB1 + pn); rB3 = h_ld(hB1 + pn + 1);
        __builtin_amdgcn_sched_barrier(0);
    }
}

// Head: logits = h_final @ W_out^T, softmax. One wave per batch row.
__global__ void head_kernel(const float* __restrict__ hfin,
                            const float* __restrict__ W_out,
                            float* __restrict__ out)
{
    const int bidx = blockIdx.x;
    const int l    = threadIdx.x;      // 0..63
    float hv[8];
    #pragma unroll
    for (int j = 0; j < 8; ++j) hv[j] = hfin[bidx * 512 + j * 64 + l];
    __shared__ float logits[L_];
    for (int o = 0; o < L_; ++o) {
        float p = 0.f;
        #pragma unroll
        for (int j = 0; j < 8; ++j) p += hv[j] * W_out[o * 512 + j * 64 + l];
        #pragma unroll
        for (int off = 32; off; off >>= 1) p += __shfl_down(p, off, 64);
        if (l == 0) logits[o] = p;
    }
    __syncthreads();
    if (l == 0) {
        float mx = logits[0];
        for (int o = 1; o < L_; ++o) mx = fmaxf(mx, logits[o]);
        float e[L_], sum = 0.f;
        for (int o = 0; o < L_; ++o) { e[o] = __expf(logits[o] - mx); sum += e[o]; }
        const float inv = 1.f / sum;
        for (int o = 0; o < L_; ++o) out[bidx * L_ + o] = e[o] * inv;
    }
}

extern "C" void kernel_launch(void* const* d_in, const int* in_sizes, int n_in,
                              void* d_out, int out_size, void* d_ws, size_t ws_size,
                              hipStream_t stream) {
    const float* x     = (const float*)d_in[0];
    const float* W_ih  = (const float*)d_in[1];
    const float* W_hh  = (const float*)d_in[2];
    const float* bias  = (const float*)d_in[3];
    const float* W_out = (const float*)d_in[4];
    float* out = (float*)d_out;

    // ws: h_buf [2][128][512] bf16 (262144) | flags [8][128] u32 (4096) |
    //     hfin [128][512] f32 (262144)
    char* ws = (char*)d_ws;
    u64*          h_buf = (u64*)ws;
    unsigned int* flags = (unsigned int*)(ws + 262144);
    float*        hfin  = (float*)(ws + 262144 + 4096);

    hipMemsetAsync(ws, 0, 262144 + 4096, stream);

    void* args[] = { (void*)&x, (void*)&W_ih, (void*)&W_hh, (void*)&bias,
                     (void*)&h_buf, (void*)&flags, (void*)&hfin };
    hipLaunchCooperativeKernel((void*)lstm_kernel, dim3(NPAIR * NS), dim3(512),
                               args, 0, stream);
    head_kernel<<<dim3(B_), dim3(64), 0, stream>>>(hfin, W_out, out);
}